// Round 11
// baseline (394.317 us; speedup 1.0000x reference)
//
#include <hip/hip_runtime.h>

#define N_NODES 50000
#define N_EDGES 800000
#define D 128
#define PLANE ((size_t)N_NODES * D)
#define NCHUNK ((N_NODES + 255) / 256)  // 196
#define MB64 ((N_NODES + 63) / 64)      // 782 M-tiles
#define FVB_ELEMS ((size_t)3 * MB64 * 256 * 32)  // padded! 19,218,432 > 3*PLANE

typedef float f32x4 __attribute__((ext_vector_type(4)));
typedef short bf16x8 __attribute__((ext_vector_type(8)));

__device__ __forceinline__ unsigned short f2bf(float x) {
  unsigned int u = __float_as_uint(x);
  u += 0x7FFFu + ((u >> 16) & 1u);  // RNE
  return (unsigned short)(u >> 16);
}
__device__ __forceinline__ float bf2f(unsigned short h) {
  return __uint_as_float((unsigned int)h << 16);
}

// ---------------- CSR build ----------------

__global__ __launch_bounds__(256) void scan_local(const int* __restrict__ cnt,
                                                  int* __restrict__ local,
                                                  int* __restrict__ partial) {
  __shared__ int s[256];
  int t = threadIdx.x;
  int i = blockIdx.x * 256 + t;
  int v = (i < N_NODES) ? cnt[i] : 0;
  s[t] = v;
  __syncthreads();
  for (int off = 1; off < 256; off <<= 1) {
    int tmp = (t >= off) ? s[t - off] : 0;
    __syncthreads();
    s[t] += tmp;
    __syncthreads();
  }
  if (i < N_NODES) local[i] = s[t] - v;
  if (t == 255) partial[blockIdx.x] = s[255];
}

__global__ __launch_bounds__(256) void scan_chunks(const int* __restrict__ partial,
                                                   int* __restrict__ chunk_off,
                                                   int* __restrict__ rowptr) {
  __shared__ int s[256];
  int t = threadIdx.x;
  int v = (t < NCHUNK) ? partial[t] : 0;
  s[t] = v;
  __syncthreads();
  for (int off = 1; off < 256; off <<= 1) {
    int tmp = (t >= off) ? s[t - off] : 0;
    __syncthreads();
    s[t] += tmp;
    __syncthreads();
  }
  if (t < NCHUNK) chunk_off[t] = s[t] - v;
  if (t == 255) rowptr[N_NODES] = s[255];
}

__global__ __launch_bounds__(256) void finalize_rows(const int* __restrict__ cnt,
                                                     const int* __restrict__ local,
                                                     const int* __restrict__ chunk_off,
                                                     int* __restrict__ rowptr,
                                                     int* __restrict__ cursor,
                                                     float* __restrict__ norm) {
  int i = blockIdx.x * 256 + threadIdx.x;
  if (i < N_NODES) {
    int r = local[i] + chunk_off[blockIdx.x];
    rowptr[i] = r;
    cursor[i] = r;
    int d = cnt[i];
    if (d < 1) d = 1;
    norm[i] = rsqrtf((float)d);
  }
}

__global__ __launch_bounds__(256) void fill_csr(const int* __restrict__ src,
                                                const int* __restrict__ dst,
                                                int* __restrict__ cursor,
                                                int* __restrict__ col) {
  int e = blockIdx.x * blockDim.x + threadIdx.x;
  if (e < N_EDGES) {
    int pos = atomicAdd(&cursor[dst[e]], 1);
    col[pos] = src[e];
  }
}

// ---------------- fused prep: feats->bf16 + weight transposes + degree count ----------------
// bt layout per matrix: [stack][n][k] bf16 (128x128 = 32 KB/stack)

#define CONV_THREADS ((int)(PLANE / 4))            // 1,600,000
#define WT_THREADS (3 * 3 * 128 * 128)             // 147,456
#define PREP_TOTAL (CONV_THREADS + WT_THREADS + N_EDGES)

__global__ __launch_bounds__(256) void prep_all(const float* __restrict__ feats,
                                                const float* __restrict__ w0,
                                                const float* __restrict__ w,
                                                const float* __restrict__ v,
                                                const int* __restrict__ dst,
                                                unsigned short* __restrict__ feats_bf,
                                                unsigned short* __restrict__ btw0,
                                                unsigned short* __restrict__ btw,
                                                unsigned short* __restrict__ btv,
                                                int* __restrict__ cnt) {
  int idx = blockIdx.x * 256 + threadIdx.x;
  if (idx < CONV_THREADS) {
    float4 x = ((const float4*)feats)[idx];
    ushort4 o;
    o.x = f2bf(x.x);
    o.y = f2bf(x.y);
    o.z = f2bf(x.z);
    o.w = f2bf(x.w);
    ((ushort4*)feats_bf)[idx] = o;
    return;
  }
  idx -= CONV_THREADS;
  if (idx < WT_THREADS) {
    int buf = idx / 49152;
    int rem = idx - buf * 49152;
    int stack = rem >> 14;
    int r2 = rem & 16383;
    int n = r2 >> 7;
    int k = r2 & 127;
    const float* srcm = (buf == 0) ? w0 : (buf == 1) ? w : v;
    unsigned short* dstb = (buf == 0) ? btw0 : (buf == 1) ? btw : btv;
    dstb[(size_t)stack * 16384 + (size_t)n * 128 + k] =
        f2bf(srcm[(size_t)stack * 16384 + (size_t)k * 128 + n]);
    return;
  }
  idx -= WT_THREADS;
  if (idx < N_EDGES) atomicAdd(&cnt[dst[idx]], 1);
}

// ---------------- SpMM body (R6-proven): 4 edges/iter x unroll 4, 16 B/lane ----------------

template <int NK>
__device__ __forceinline__ void spmm_body(const unsigned short* const* hs,
                                          const float* __restrict__ norm,
                                          const int* __restrict__ rowptr,
                                          const int* __restrict__ col,
                                          unsigned short* const* outs, int bx) {
  int row = bx * 4 + ((int)threadIdx.x >> 6);
  if (row >= N_NODES) return;
  int lane = threadIdx.x & 63;
  int sub = lane >> 4;
  int c16 = lane & 15;
  int beg = rowptr[row], end = rowptr[row + 1];

  float acc[NK][8];
#pragma unroll
  for (int m = 0; m < NK; ++m)
#pragma unroll
    for (int j = 0; j < 8; ++j) acc[m][j] = 0.f;

#pragma unroll 4
  for (int e = beg; e < end; e += 4) {
    int eidx = e + sub;
    bool valid = eidx < end;
    int s = valid ? col[eidx] : 0;
    float wgt = valid ? norm[s] : 0.f;
    size_t base = (size_t)s * D + c16 * 8;
#pragma unroll
    for (int m = 0; m < NK; ++m) {
      bf16x8 hv = *(const bf16x8*)(hs[m] + base);
#pragma unroll
      for (int j = 0; j < 8; ++j)
        acc[m][j] = fmaf(wgt, bf2f((unsigned short)hv[j]), acc[m][j]);
    }
  }

#pragma unroll
  for (int m = 0; m < NK; ++m)
#pragma unroll
    for (int j = 0; j < 8; ++j) {
      float vv = acc[m][j];
      vv += __shfl_xor(vv, 16);
      vv += __shfl_xor(vv, 32);
      acc[m][j] = vv;
    }

  if (sub == 0) {
    float nd = norm[row];
#pragma unroll
    for (int m = 0; m < NK; ++m) {
      bf16x8 ov;
#pragma unroll
      for (int j = 0; j < 8; ++j) ov[j] = (short)f2bf(acc[m][j] * nd);
      *(bf16x8*)(outs[m] + (size_t)row * D + c16 * 8) = ov;
    }
  }
}

// ---------------- K=128 MFMA tile machinery ----------------
// B-tile: [128n][128k] bf16 = 32 KB LDS, XOR-swizzled (chunk c of row n at
// c ^ (n & 15)) -> fragment reads bank-spread. Fragments (m89/m120-verified):
// A[m=lane&15][k=(lane>>4)*8+j]; B-frag = Bt[n=lane&15][k..];
// C/D col=lane&15, row=(lane>>4)*4+reg.

__device__ __forceinline__ void stage_Bq(unsigned short (*Bs)[128],
                                         const unsigned short* __restrict__ Btg,
                                         int tid) {
#pragma unroll
  for (int i = 0; i < 8; ++i) {
    int t = tid + i * 256;  // 0..2047 16B-chunks
    int n = t >> 4;         // 0..127
    int c = t & 15;
    int cs = c ^ (n & 15);  // swizzle
    *(bf16x8*)&Bs[n][cs * 8] = *(const bf16x8*)(Btg + (size_t)n * 128 + c * 8);
  }
}

__device__ __forceinline__ bf16x8 read_Bq(const unsigned short (*Bs)[128], int n,
                                          int chunk) {
  return *(const bf16x8*)&Bs[n][(chunk ^ (n & 15)) * 8];
}

// ---------------- hybrid: FV[k] = feats @ v[k] (blocks 0..MB64-1, fragment-blocked
// output) co-scheduled with spmm1 feats->P (remaining blocks) ----------------

__global__ __launch_bounds__(256) void hybrid_fv_spmm1(
    const unsigned short* __restrict__ feats_bf,
    const unsigned short* __restrict__ btv,
    const float* __restrict__ norm, const int* __restrict__ rowptr,
    const int* __restrict__ col,
    unsigned short* __restrict__ FVb,  // [stk][MB64][256][32]
    unsigned short* __restrict__ P) {
  __shared__ unsigned short Bs[128][128];

  if (blockIdx.x < MB64) {
    int tid = threadIdx.x;
    int lane = tid & 63;
    int wv = tid >> 6;
    int ln15 = lane & 15;
    int g = lane >> 4;

    int m0 = blockIdx.x * 64 + wv * 16;
    int r0 = m0 + ln15;
    if (r0 >= N_NODES) r0 = N_NODES - 1;

    bf16x8 a[4];
#pragma unroll
    for (int s = 0; s < 4; ++s)
      a[s] = *(const bf16x8*)(feats_bf + (size_t)r0 * 128 + g * 8 + s * 32);

    for (int stk = 0; stk < 3; ++stk) {
      if (stk) __syncthreads();
      stage_Bq(Bs, btv + (size_t)stk * 16384, tid);
      __syncthreads();

      f32x4 acc[8];
#pragma unroll
      for (int nt = 0; nt < 8; ++nt) acc[nt] = (f32x4)(0.f);

#pragma unroll
      for (int s = 0; s < 4; ++s) {
#pragma unroll
        for (int nt = 0; nt < 8; ++nt) {
          bf16x8 bfr = read_Bq(Bs, nt * 16 + ln15, s * 4 + g);
          acc[nt] = __builtin_amdgcn_mfma_f32_16x16x32_bf16(a[s], bfr, acc[nt], 0, 0, 0);
        }
      }

      unsigned short buf[32];
#pragma unroll
      for (int nt = 0; nt < 8; ++nt)
#pragma unroll
        for (int r = 0; r < 4; ++r) buf[nt * 4 + r] = f2bf(acc[nt][r]);
      bf16x8* dst =
          (bf16x8*)(FVb + (((size_t)stk * MB64 + blockIdx.x) * 256 + tid) * 32);
#pragma unroll
      for (int q = 0; q < 4; ++q) dst[q] = ((bf16x8*)buf)[q];
    }
  } else {
    const unsigned short* hs[1] = {feats_bf};
    unsigned short* outs[1] = {P};
    spmm_body<1>(hs, norm, rowptr, col, outs, blockIdx.x - MB64);
  }
}

// ---------------- spmm3 standalone ----------------

__global__ __launch_bounds__(256) void spmm3(
    const unsigned short* __restrict__ h0, const unsigned short* __restrict__ h1,
    const unsigned short* __restrict__ h2, const float* __restrict__ norm,
    const int* __restrict__ rowptr, const int* __restrict__ col,
    unsigned short* __restrict__ o0, unsigned short* __restrict__ o1,
    unsigned short* __restrict__ o2) {
  const unsigned short* hs[3] = {h0, h1, h2};
  unsigned short* outs[3] = {o0, o1, o2};
  spmm_body<3>(hs, norm, rowptr, col, outs, blockIdx.x);
}

// ---------------- layer-1 GEMM: h1[k] = relu(P @ w0[k] + FV[k] + b0 + bv) ----------------

__global__ __launch_bounds__(256) void gemm_h1(
    const unsigned short* __restrict__ P, const unsigned short* __restrict__ btw0,
    const unsigned short* __restrict__ FVb,
    const float* __restrict__ b0, const float* __restrict__ bv,
    unsigned short* __restrict__ o0, unsigned short* __restrict__ o1,
    unsigned short* __restrict__ o2) {
  __shared__ unsigned short Bs[128][128];
  unsigned short* outs[3] = {o0, o1, o2};

  int tid = threadIdx.x;
  int lane = tid & 63;
  int wv = tid >> 6;
  int ln15 = lane & 15;
  int g = lane >> 4;

  int m0 = blockIdx.x * 64 + wv * 16;
  int r0 = m0 + ln15;
  if (r0 >= N_NODES) r0 = N_NODES - 1;

  bf16x8 a[4];
#pragma unroll
  for (int s = 0; s < 4; ++s)
    a[s] = *(const bf16x8*)(P + (size_t)r0 * 128 + g * 8 + s * 32);

  for (int stk = 0; stk < 3; ++stk) {
    if (stk) __syncthreads();
    stage_Bq(Bs, btw0 + (size_t)stk * 16384, tid);
    __syncthreads();

    f32x4 acc[8];
#pragma unroll
    for (int nt = 0; nt < 8; ++nt) acc[nt] = (f32x4)(0.f);

#pragma unroll
    for (int s = 0; s < 4; ++s) {
#pragma unroll
      for (int nt = 0; nt < 8; ++nt) {
        bf16x8 bfr = read_Bq(Bs, nt * 16 + ln15, s * 4 + g);
        acc[nt] = __builtin_amdgcn_mfma_f32_16x16x32_bf16(a[s], bfr, acc[nt], 0, 0, 0);
      }
    }

    // FV fragment-blocked load (same grid geometry as producer)
    bf16x8 fv[4];
    const bf16x8* fvp =
        (const bf16x8*)(FVb + (((size_t)stk * MB64 + blockIdx.x) * 256 + tid) * 32);
#pragma unroll
    for (int q = 0; q < 4; ++q) fv[q] = fvp[q];

    unsigned short* outp = outs[stk];
#pragma unroll
    for (int nt = 0; nt < 8; ++nt) {
      int colj = nt * 16 + ln15;
      float bsum = b0[stk * 128 + colj] + bv[stk * 128 + colj];
#pragma unroll
      for (int r = 0; r < 4; ++r) {
        int mA = m0 + g * 4 + r;
        if (mA < N_NODES) {
          int vi = nt * 4 + r;
          float fvv = bf2f((unsigned short)fv[vi >> 3][vi & 7]);
          float x = acc[nt][r] + fvv + bsum;
          outp[(size_t)mA * 128 + colj] = f2bf(x > 0.f ? x : 0.f);
        }
      }
    }
  }
}

// ---------------- layer-2 GEMM: out = (1/3) sum_k relu(agg[k] @ w[k] + FV[k] + bw + bv) ----

__global__ __launch_bounds__(256) void gemm_out(
    const unsigned short* __restrict__ a0, const unsigned short* __restrict__ a1,
    const unsigned short* __restrict__ a2, const unsigned short* __restrict__ btw,
    const unsigned short* __restrict__ FVb,
    const float* __restrict__ bwp, const float* __restrict__ bvp,
    float* __restrict__ outp) {
  __shared__ unsigned short Bs[128][128];
  const unsigned short* aggs[3] = {a0, a1, a2};

  int tid = threadIdx.x;
  int lane = tid & 63;
  int wv = tid >> 6;
  int ln15 = lane & 15;
  int g = lane >> 4;

  int m0 = blockIdx.x * 64 + wv * 16;
  int r0 = m0 + ln15;
  if (r0 >= N_NODES) r0 = N_NODES - 1;

  f32x4 sum[8];
#pragma unroll
  for (int nt = 0; nt < 8; ++nt) sum[nt] = (f32x4)(0.f);

  for (int stk = 0; stk < 3; ++stk) {
    if (stk) __syncthreads();
    stage_Bq(Bs, btw + (size_t)stk * 16384, tid);
    __syncthreads();

    bf16x8 a[4];
#pragma unroll
    for (int s = 0; s < 4; ++s)
      a[s] = *(const bf16x8*)(aggs[stk] + (size_t)r0 * 128 + g * 8 + s * 32);

    f32x4 acc[8];
#pragma unroll
    for (int nt = 0; nt < 8; ++nt) acc[nt] = (f32x4)(0.f);

#pragma unroll
    for (int s = 0; s < 4; ++s) {
#pragma unroll
      for (int nt = 0; nt < 8; ++nt) {
        bf16x8 bfr = read_Bq(Bs, nt * 16 + ln15, s * 4 + g);
        acc[nt] = __builtin_amdgcn_mfma_f32_16x16x32_bf16(a[s], bfr, acc[nt], 0, 0, 0);
      }
    }

    bf16x8 fv[4];
    const bf16x8* fvp =
        (const bf16x8*)(FVb + (((size_t)stk * MB64 + blockIdx.x) * 256 + tid) * 32);
#pragma unroll
    for (int q = 0; q < 4; ++q) fv[q] = fvp[q];

#pragma unroll
    for (int nt = 0; nt < 8; ++nt) {
      int colj = nt * 16 + ln15;
      float bsum = bwp[stk * 128 + colj] + bvp[stk * 128 + colj];
#pragma unroll
      for (int r = 0; r < 4; ++r) {
        int vi = nt * 4 + r;
        float fvv = bf2f((unsigned short)fv[vi >> 3][vi & 7]);
        float x = acc[nt][r] + fvv + bsum;
        sum[nt][r] += (x > 0.f ? x : 0.f);
      }
    }
  }

  const float sc = 1.0f / 3.0f;
#pragma unroll
  for (int nt = 0; nt < 8; ++nt) {
    int colj = nt * 16 + ln15;
#pragma unroll
    for (int r = 0; r < 4; ++r) {
      int mA = m0 + g * 4 + r;
      if (mA < N_NODES) outp[(size_t)mA * 128 + colj] = sum[nt][r] * sc;
    }
  }
}

// ---------------- launcher ----------------

extern "C" void kernel_launch(void* const* d_in, const int* in_sizes, int n_in,
                              void* d_out, int out_size, void* d_ws, size_t ws_size,
                              hipStream_t stream) {
  const float* feats = (const float*)d_in[0];
  const int* src = (const int*)d_in[1];
  const int* dst = (const int*)d_in[2];
  const float* w0 = (const float*)d_in[3];
  const float* b0 = (const float*)d_in[4];
  const float* w = (const float*)d_in[5];
  const float* bw = (const float*)d_in[6];
  const float* v = (const float*)d_in[7];
  const float* bv = (const float*)d_in[8];
  float* out = (float*)d_out;

  char* ws = (char*)d_ws;
  size_t off = 0;
  auto alloc = [&](size_t bytes) {
    void* p = ws + off;
    off += (bytes + 255) & ~(size_t)255;
    return p;
  };
  int* cnt = (int*)alloc(N_NODES * 4);
  int* local = (int*)alloc(N_NODES * 4);
  int* partial = (int*)alloc(NCHUNK * 4);
  int* chunk_off = (int*)alloc(NCHUNK * 4);
  float* norm = (float*)alloc(N_NODES * 4);
  int* rowptr = (int*)alloc((N_NODES + 1) * 4);
  int* cursor = (int*)alloc(N_NODES * 4);
  int* col = (int*)alloc(N_EDGES * 4);
  unsigned short* btw0 = (unsigned short*)alloc(3 * 16384 * 2);
  unsigned short* btw = (unsigned short*)alloc(3 * 16384 * 2);
  unsigned short* btv = (unsigned short*)alloc(3 * 16384 * 2);

  size_t pb = PLANE * 2;  // bf16 plane bytes
  // plane pool with aliasing:
  //  p0: feats_bf -> h1[2]   p1: P -> agg[0]
  //  FVb: fragment-blocked FV, PADDED size (MB64*64 rows = 50048 > N_NODES!)
  //  p5: h1[0]  p6: h1[1]   p7: agg[1]  p8: agg[2]
  unsigned short* p0 = (unsigned short*)alloc(pb);
  unsigned short* p1 = (unsigned short*)alloc(pb);
  unsigned short* FVb = (unsigned short*)alloc(FVB_ELEMS * 2);  // R10 bug: was 3*pb (too small)
  unsigned short* p5 = (unsigned short*)alloc(pb);
  unsigned short* p6 = (unsigned short*)alloc(pb);
  unsigned short* p7 = (unsigned short*)alloc(pb);
  unsigned short* p8 = (unsigned short*)alloc(pb);

  unsigned short* feats_bf = p0;
  unsigned short* P_bf = p1;
  unsigned short *h1a = p5, *h1b = p6, *h1c = p0;   // p0 dead after hybrid
  unsigned short *agga = p1, *aggb = p7, *aggc = p8;  // p1 dead after gemm_h1

  hipMemsetAsync(cnt, 0, N_NODES * 4, stream);

  dim3 blk(256);
  prep_all<<<(PREP_TOTAL + 255) / 256, blk, 0, stream>>>(feats, w0, w, v, dst, feats_bf,
                                                         btw0, btw, btv, cnt);
  scan_local<<<NCHUNK, blk, 0, stream>>>(cnt, local, partial);
  scan_chunks<<<1, blk, 0, stream>>>(partial, chunk_off, rowptr);
  finalize_rows<<<NCHUNK, blk, 0, stream>>>(cnt, local, chunk_off, rowptr, cursor, norm);
  fill_csr<<<(N_EDGES + 255) / 256, blk, 0, stream>>>(src, dst, cursor, col);

  int sblocks = (N_NODES + 3) / 4;

  // FV[k] = feats @ v[k] (782 gemm-role blocks, dispatched first)
  // co-scheduled with P = propagate(feats) (12500 spmm-role blocks)
  hybrid_fv_spmm1<<<MB64 + sblocks, blk, 0, stream>>>(feats_bf, btv, norm, rowptr, col,
                                                      FVb, P_bf);
  // h1[k] = relu(P @ w0[k] + FV[k] + b0[k] + bv[k])
  gemm_h1<<<MB64, blk, 0, stream>>>(P_bf, btw0, FVb, b0, bv, h1a, h1b, h1c);
  // agg[k] = propagate(h1[k])
  spmm3<<<sblocks, blk, 0, stream>>>(h1a, h1b, h1c, norm, rowptr, col, agga, aggb, aggc);
  // out = (1/3) sum_k relu(agg[k] @ w[k] + FV[k] + bw[k] + bv[k])
  gemm_out<<<MB64, blk, 0, stream>>>(agga, aggb, aggc, btw, FVb, bw, bv, out);
}